// Round 21
// baseline (301.878 us; speedup 1.0000x reference)
//
#include <hip/hip_runtime.h>
#include <hip/hip_bf16.h>
#include <math.h>

// QwenStyleSparseMoEBlock: T=4096, D=1024, F=2048, E=4, top-2.
// R21: GEMM2 rebuilt as a de-GELU'd copy of the proven GEMM1 kernel:
// 256x256xBK64, 8 waves, 128KiB dbuf, T3-min counted schedule, G4 swizzle.
// Rationale: per drain-stall GEMM1 amortizes 64 MFMA, old 128^2 GEMM2 only 32
// — exactly the observed 2x per-FLOP gap (620 vs ~350 TF). Split-K x2, grid
// 288 = 8 XCD x 36 (kh/bn/mt decode; each XCD: 1 bn-slice x 4 experts = 4MB
// Wdt = L2-resident). Uses gemm1's pad-256 tile decode (off[4..8]).
// GEMM1/routing/tcvt/combine = R14-exact (288.5us best, absmax 4.15e-3).

typedef float  f32x4 __attribute__((ext_vector_type(4)));
typedef short  s16x8 __attribute__((ext_vector_type(8)));

__device__ __forceinline__ unsigned short f2bf(float f) {
  union { float f; unsigned int u; } v; v.f = f;
  return (unsigned short)((v.u + 0x7fffu + ((v.u >> 16) & 1u)) >> 16);  // RNE
}
__device__ __forceinline__ float bf2f(unsigned short b) {
  union { unsigned int u; float f; } v; v.u = ((unsigned int)b) << 16;
  return v.f;
}

__device__ __forceinline__ void glds16(const void* g, void* l) {
  __builtin_amdgcn_global_load_lds(
      (const __attribute__((address_space(1))) void*)g,
      (__attribute__((address_space(3))) void*)l, 16, 0, 0);
}

// ---------------- routing + X conversion + pos ----------------
__global__ void k_routing(const float* __restrict__ x, const float* __restrict__ wg,
                          float* __restrict__ cw, int* __restrict__ idx,
                          int* __restrict__ cnt, unsigned short* __restrict__ Xb,
                          int4* __restrict__ pos) {
  const int lane = threadIdx.x & 63;
  const int tok  = blockIdx.x * 4 + (threadIdx.x >> 6);
  const float4* X4 = (const float4*)x + (size_t)tok * 256;
  const float4* W4 = (const float4*)wg;
  ushort4* O4 = (ushort4*)Xb + (size_t)tok * 256;
  float a0 = 0.f, a1 = 0.f, a2 = 0.f, a3 = 0.f;
#pragma unroll
  for (int j = 0; j < 4; ++j) {
    const int d4 = j * 64 + lane;
    const float4 v = X4[d4];
    ushort4 o;
    o.x = f2bf(v.x); o.y = f2bf(v.y); o.z = f2bf(v.z); o.w = f2bf(v.w);
    O4[d4] = o;
    float4 w;
    w = W4[0 * 256 + d4]; a0 += v.x * w.x + v.y * w.y + v.z * w.z + v.w * w.w;
    w = W4[1 * 256 + d4]; a1 += v.x * w.x + v.y * w.y + v.z * w.z + v.w * w.w;
    w = W4[2 * 256 + d4]; a2 += v.x * w.x + v.y * w.y + v.z * w.z + v.w * w.w;
    w = W4[3 * 256 + d4]; a3 += v.x * w.x + v.y * w.y + v.z * w.z + v.w * w.w;
  }
#pragma unroll
  for (int off = 32; off; off >>= 1) {
    a0 += __shfl_xor(a0, off);
    a1 += __shfl_xor(a1, off);
    a2 += __shfl_xor(a2, off);
    a3 += __shfl_xor(a3, off);
  }
  if (lane == 0) {
    float l[4] = {a0, a1, a2, a3};
    const float m = fmaxf(fmaxf(l[0], l[1]), fmaxf(l[2], l[3]));
    float p[4];
#pragma unroll
    for (int e = 0; e < 4; ++e) p[e] = expf(l[e] - m);
    int i1 = 0; float b1 = p[0];
#pragma unroll
    for (int e = 1; e < 4; ++e) if (p[e] > b1) { b1 = p[e]; i1 = e; }
    int i2 = -1; float b2 = -1.f;
#pragma unroll
    for (int e = 0; e < 4; ++e) if (e != i1 && p[e] > b2) { b2 = p[e]; i2 = e; }
    const float inv = 1.f / (b1 + b2);
    float o[4] = {0.f, 0.f, 0.f, 0.f};
    o[i1] = b1 * inv; o[i2] = b2 * inv;
    *(float4*)(cw + (size_t)tok * 4) = make_float4(o[0], o[1], o[2], o[3]);
    const int p1 = atomicAdd(&cnt[i1], 1); idx[i1 * 4096 + p1] = tok;
    const int p2 = atomicAdd(&cnt[i2], 1); idx[i2 * 4096 + p2] = tok;
    pos[tok] = make_int4(i1, p1, i2, p2);
  }
}

// off[0..3]=row base (pad-256); off[4..8]=prefix of ceil256 tiles
__global__ void k_offsets(const int* __restrict__ cnt, int* __restrict__ off) {
  if (threadIdx.x == 0 && blockIdx.x == 0) {
    int o = 0, q = 0;
#pragma unroll
    for (int e = 0; e < 4; ++e) {
      off[e] = o; off[4 + e] = q;
      o += (cnt[e] + 255) & ~255;
      q += (cnt[e] + 255) >> 8;
    }
    off[8] = q;
  }
}

// ---------------- weights -> transposed bf16; gate/up interleaved into Wcat ----------------
__global__ void k_tcvt_all(const float* __restrict__ wgp, const float* __restrict__ wup,
                           const float* __restrict__ wdp,
                           unsigned short* __restrict__ Wcat,
                           unsigned short* __restrict__ Wdt) {
  __shared__ float t[64][65];
  const int z = blockIdx.z;
  const int tx = threadIdx.x, ty = threadIdx.y;
  const float* in; unsigned short* outp; int R, C, c0, r0, cat = 0, addup = 0;
  if (z < 8) {
    R = 1024; C = 2048;
    const int e = z & 3;
    in   = (z < 4 ? wgp : wup) + (size_t)e * 1024 * 2048;
    outp = Wcat + (size_t)e * 4096 * 1024;
    c0 = blockIdx.x * 64; r0 = blockIdx.y * 64;
    cat = 1; addup = (z >= 4) ? 16 : 0;
  } else {
    R = 2048; C = 1024;
    const int e = z & 3;
    in   = wdp + (size_t)e * 2048 * 1024;
    outp = Wdt + (size_t)e * 2048 * 1024;
    c0 = blockIdx.y * 64; r0 = blockIdx.x * 64;
  }
#pragma unroll
  for (int i = 0; i < 16; ++i) {
    const int r = i * 4 + ty;
    t[r][tx] = in[(size_t)(r0 + r) * C + c0 + tx];
  }
  __syncthreads();
#pragma unroll
  for (int i = 0; i < 16; ++i) {
    const int cc = i * 4 + ty;
    const int f = c0 + cc;
    const int orow = cat ? (((f >> 4) << 5) + (f & 15) + addup) : f;
    outp[(size_t)orow * R + r0 + tx] = f2bf(t[tx][cc]);
  }
}

// ---------------- GEMM1: H = gelu(Xg@Wg)*(Xg@Wu), 256x256, T3-min counted ----------------
// grid 576 = 16 bn x 36 mt, bn-major XCD chunks (chunk=72)   [R14-exact]
__global__ __launch_bounds__(512, 2)
void k_gemm1(const unsigned short* __restrict__ Xb,
             const unsigned short* __restrict__ Wcat,
             unsigned short* __restrict__ H,
             const int* __restrict__ idx, const int* __restrict__ cnt,
             const int* __restrict__ off) {
  const int w0 = (blockIdx.x & 7) * 72 + (blockIdx.x >> 3);
  const int bn = w0 / 36, mt = w0 % 36;
  const int* t1 = off + 4;
  if (mt >= t1[4]) return;
  const int e = (mt >= t1[1]) + (mt >= t1[2]) + (mt >= t1[3]);
  const int local = mt - t1[e];
  const int cn = cnt[e];
  const int lr0 = local * 256;
  const int hrow0 = off[e] + lr0;

  __shared__ __align__(16) unsigned short lds[2][2][256 * 64];  // 128 KiB

  const int tid = threadIdx.x;
  const int lane = tid & 63, wv = tid >> 6;
  const int wm = wv >> 2, wn = wv & 3;            // 2 x 4 waves
  const int l15 = lane & 15;
  const int kb0 = ((lane >> 4) * 16) ^ ((lane & 7) << 4);
  const int kb1 = kb0 ^ 64;
  const int lrow = lane >> 3;
  const int scol = ((lane & 7) ^ lrow) * 8;
  const int wbase = wv * 8;

  int tk[4];
#pragma unroll
  for (int j = 0; j < 4; ++j)
    tk[j] = idx[e * 4096 + min(lr0 + j * 64 + wbase + lrow, cn - 1)];

  const unsigned short* Wb = Wcat + (size_t)e * 4096 * 1024 + (size_t)(bn * 256) * 1024;

  f32x4 acc[8][4] = {};

#pragma unroll
  for (int j = 0; j < 4; ++j)
    glds16(Xb + (size_t)tk[j] * 1024 + scol, &lds[0][0][(j * 64 + wbase) * 64]);
#pragma unroll
  for (int j = 0; j < 4; ++j)
    glds16(Wb + (size_t)(j * 64 + wbase + lrow) * 1024 + scol, &lds[0][1][(j * 64 + wbase) * 64]);

  for (int kt = 0; kt < 16; ++kt) {
    const int cur = kt & 1;
    asm volatile("s_waitcnt vmcnt(0)" ::: "memory");
    asm volatile("s_barrier" ::: "memory");
    if (kt < 15) {
      const int ko = (kt + 1) * 64;
#pragma unroll
      for (int j = 0; j < 4; ++j)
        glds16(Xb + (size_t)tk[j] * 1024 + ko + scol, &lds[cur ^ 1][0][(j * 64 + wbase) * 64]);
#pragma unroll
      for (int j = 0; j < 4; ++j)
        glds16(Wb + (size_t)(j * 64 + wbase + lrow) * 1024 + ko + scol, &lds[cur ^ 1][1][(j * 64 + wbase) * 64]);
    }
    const char* Ab = (const char*)lds[cur][0];
    const char* Bb = (const char*)lds[cur][1];
    s16x8 bfr[4][2];
#pragma unroll
    for (int ni = 0; ni < 4; ++ni) {
      const int row = wn * 64 + ni * 16 + l15;
      bfr[ni][0] = *(const s16x8*)(Bb + row * 128 + kb0);
      bfr[ni][1] = *(const s16x8*)(Bb + row * 128 + kb1);
    }
#pragma unroll
    for (int p = 0; p < 4; ++p) {
      const int r0a = wm * 128 + (2 * p) * 16 + l15;
      const int r1a = wm * 128 + (2 * p + 1) * 16 + l15;
      const s16x8 a0k0 = *(const s16x8*)(Ab + r0a * 128 + kb0);
      const s16x8 a0k1 = *(const s16x8*)(Ab + r0a * 128 + kb1);
      const s16x8 a1k0 = *(const s16x8*)(Ab + r1a * 128 + kb0);
      const s16x8 a1k1 = *(const s16x8*)(Ab + r1a * 128 + kb1);
      __builtin_amdgcn_s_setprio(1);
#pragma unroll
      for (int ni = 0; ni < 4; ++ni) {
        acc[2 * p][ni]     = __builtin_amdgcn_mfma_f32_16x16x32_bf16(a0k0, bfr[ni][0], acc[2 * p][ni], 0, 0, 0);
        acc[2 * p][ni]     = __builtin_amdgcn_mfma_f32_16x16x32_bf16(a0k1, bfr[ni][1], acc[2 * p][ni], 0, 0, 0);
        acc[2 * p + 1][ni] = __builtin_amdgcn_mfma_f32_16x16x32_bf16(a1k0, bfr[ni][0], acc[2 * p + 1][ni], 0, 0, 0);
        acc[2 * p + 1][ni] = __builtin_amdgcn_mfma_f32_16x16x32_bf16(a1k1, bfr[ni][1], acc[2 * p + 1][ni], 0, 0, 0);
      }
      __builtin_amdgcn_s_setprio(0);
    }
  }

  const int rbase = hrow0 + wm * 128;
#pragma unroll
  for (int mi = 0; mi < 8; ++mi)
#pragma unroll
    for (int q = 0; q < 2; ++q)
#pragma unroll
      for (int r = 0; r < 4; ++r) {
        const int row = rbase + mi * 16 + (lane >> 4) * 4 + r;
        const int col = bn * 128 + wn * 32 + q * 16 + l15;
        const float g = acc[mi][2 * q][r];
        const float u = acc[mi][2 * q + 1][r];
        const float h = 0.5f * g * (1.0f + erff(g * 0.70710678118654752f)) * u;
        H[(size_t)row * 2048 + col] = f2bf(h);
      }
}

// ---------------- GEMM2: Y[kh] = H_e[:,kh] @ Wd_e[kh,:], 256x256 ----------------
// grid 288 = 8 XCD x 36: w = kh*144 + bn*36 + mt (bn-major per XCD; each XCD
// owns 1 bn-slice x all experts = 4MB Wdt = L2-resident). Same kernel shape
// as gemm1 (64 MFMA per drain), minus gather and gelu.
__global__ __launch_bounds__(512, 2)
void k_gemm2(const unsigned short* __restrict__ H,
             const unsigned short* __restrict__ Wdt,
             const int* __restrict__ cnt, const int* __restrict__ off,
             unsigned short* __restrict__ Y) {
  const int w = (blockIdx.x & 7) * 36 + (blockIdx.x >> 3);   // bijective, 288=8*36
  const int kh = (w >= 144) ? 1 : 0;
  const int w2 = w - kh * 144;
  const int bn = w2 / 36;          // 0..3 (256-wide N slices)
  const int mt = w2 % 36;
  const int* t1 = off + 4;
  if (mt >= t1[4]) return;
  const int e = (mt >= t1[1]) + (mt >= t1[2]) + (mt >= t1[3]);
  const int local = mt - t1[e];
  const int lr0 = local * 256;
  const int hrow0 = off[e] + lr0;

  __shared__ __align__(16) unsigned short lds[2][2][256 * 64];  // 128 KiB

  const int tid = threadIdx.x;
  const int lane = tid & 63, wv = tid >> 6;
  const int wm = wv >> 2, wn = wv & 3;            // 2 x 4 waves
  const int l15 = lane & 15;
  const int kb0 = ((lane >> 4) * 16) ^ ((lane & 7) << 4);
  const int kb1 = kb0 ^ 64;
  const int lrow = lane >> 3;
  const int scol = ((lane & 7) ^ lrow) * 8;
  const int wbase = wv * 8;

  const unsigned short* Ha = H + (size_t)hrow0 * 2048 + kh * 1024;
  const unsigned short* Wd = Wdt + (size_t)e * 1024 * 2048 + (size_t)(bn * 256) * 2048 + kh * 1024;

  f32x4 acc[8][4] = {};

#pragma unroll
  for (int j = 0; j < 4; ++j) {
    const int r = j * 64 + wbase;
    glds16(Ha + (size_t)(r + lrow) * 2048 + scol, &lds[0][0][r * 64]);
    glds16(Wd + (size_t)(r + lrow) * 2048 + scol, &lds[0][1][r * 64]);
  }

  for (int kt = 0; kt < 16; ++kt) {
    const int cur = kt & 1;
    asm volatile("s_waitcnt vmcnt(0)" ::: "memory");
    asm volatile("s_barrier" ::: "memory");
    if (kt < 15) {
      const int ko = (kt + 1) * 64;
#pragma unroll
      for (int j = 0; j < 4; ++j) {
        const int r = j * 64 + wbase;
        glds16(Ha + (size_t)(r + lrow) * 2048 + ko + scol, &lds[cur ^ 1][0][r * 64]);
        glds16(Wd + (size_t)(r + lrow) * 2048 + ko + scol, &lds[cur ^ 1][1][r * 64]);
      }
    }
    const char* Ab = (const char*)lds[cur][0];
    const char* Bb = (const char*)lds[cur][1];
    s16x8 bfr[4][2];
#pragma unroll
    for (int ni = 0; ni < 4; ++ni) {
      const int row = wn * 64 + ni * 16 + l15;
      bfr[ni][0] = *(const s16x8*)(Bb + row * 128 + kb0);
      bfr[ni][1] = *(const s16x8*)(Bb + row * 128 + kb1);
    }
#pragma unroll
    for (int p = 0; p < 4; ++p) {
      const int r0a = wm * 128 + (2 * p) * 16 + l15;
      const int r1a = wm * 128 + (2 * p + 1) * 16 + l15;
      const s16x8 a0k0 = *(const s16x8*)(Ab + r0a * 128 + kb0);
      const s16x8 a0k1 = *(const s16x8*)(Ab + r0a * 128 + kb1);
      const s16x8 a1k0 = *(const s16x8*)(Ab + r1a * 128 + kb0);
      const s16x8 a1k1 = *(const s16x8*)(Ab + r1a * 128 + kb1);
      __builtin_amdgcn_s_setprio(1);
#pragma unroll
      for (int ni = 0; ni < 4; ++ni) {
        acc[2 * p][ni]     = __builtin_amdgcn_mfma_f32_16x16x32_bf16(a0k0, bfr[ni][0], acc[2 * p][ni], 0, 0, 0);
        acc[2 * p][ni]     = __builtin_amdgcn_mfma_f32_16x16x32_bf16(a0k1, bfr[ni][1], acc[2 * p][ni], 0, 0, 0);
        acc[2 * p + 1][ni] = __builtin_amdgcn_mfma_f32_16x16x32_bf16(a1k0, bfr[ni][0], acc[2 * p + 1][ni], 0, 0, 0);
        acc[2 * p + 1][ni] = __builtin_amdgcn_mfma_f32_16x16x32_bf16(a1k1, bfr[ni][1], acc[2 * p + 1][ni], 0, 0, 0);
      }
      __builtin_amdgcn_s_setprio(0);
    }
  }

  // plain packed stores into this K-half's Y
  unsigned short* Yk = Y + (size_t)kh * 9216 * 1024;
  const int rbase = hrow0 + wm * 128;
#pragma unroll
  for (int mi = 0; mi < 8; ++mi)
#pragma unroll
    for (int r = 0; r < 4; ++r) {
      const int row = rbase + mi * 16 + (lane >> 4) * 4 + r;
      unsigned short* yrow = Yk + (size_t)row * 1024 + bn * 256 + wn * 64 + l15;
#pragma unroll
      for (int ni = 0; ni < 4; ++ni)
        yrow[ni * 16] = f2bf(acc[mi][ni][r]);
    }
}

// ---------------- combine: out[tok] = w1*(Y0[r1]+Y1[r1]) + w2*(Y0[r2]+Y1[r2]) ----------------
__global__ void k_combine(const unsigned short* __restrict__ Y,
                          const int4* __restrict__ pos,
                          const float* __restrict__ cw,
                          const int* __restrict__ off,
                          float* __restrict__ out) {
  const int tok = blockIdx.x;
  const int d4 = threadIdx.x;   // 256 threads, 4 floats each
  const int4 p = pos[tok];
  const int r1 = off[p.x] + p.y;
  const int r2 = off[p.z] + p.w;
  const float w1 = cw[(size_t)tok * 4 + p.x];
  const float w2 = cw[(size_t)tok * 4 + p.z];
  const unsigned short* Y1p = Y + (size_t)9216 * 1024;
  const ushort4 a1 = ((const ushort4*)(Y   + (size_t)r1 * 1024))[d4];
  const ushort4 b1 = ((const ushort4*)(Y1p + (size_t)r1 * 1024))[d4];
  const ushort4 a2 = ((const ushort4*)(Y   + (size_t)r2 * 1024))[d4];
  const ushort4 b2 = ((const ushort4*)(Y1p + (size_t)r2 * 1024))[d4];
  float4 o;
  o.x = w1 * (bf2f(a1.x) + bf2f(b1.x)) + w2 * (bf2f(a2.x) + bf2f(b2.x));
  o.y = w1 * (bf2f(a1.y) + bf2f(b1.y)) + w2 * (bf2f(a2.y) + bf2f(b2.y));
  o.z = w1 * (bf2f(a1.z) + bf2f(b1.z)) + w2 * (bf2f(a2.z) + bf2f(b2.z));
  o.w = w1 * (bf2f(a1.w) + bf2f(b1.w)) + w2 * (bf2f(a2.w) + bf2f(b2.w));
  ((float4*)(out + (size_t)tok * 1024))[d4] = o;
}

extern "C" void kernel_launch(void* const* d_in, const int* in_sizes, int n_in,
                              void* d_out, int out_size, void* d_ws, size_t ws_size,
                              hipStream_t stream) {
  const float* x     = (const float*)d_in[0];
  const float* wgate = (const float*)d_in[1];
  const float* wgp   = (const float*)d_in[2];
  const float* wup   = (const float*)d_in[3];
  const float* wdp   = (const float*)d_in[4];
  float* out = (float*)d_out;

  char* ws = (char*)d_ws;
  float* cw            = (float*)ws;                        // 64 KB
  int*   idx           = (int*)(ws + 65536);                // 64 KB
  int4*  pos           = (int4*)(ws + 131072);              // 64 KB
  int*   cnt           = (int*)(ws + 196608);               // 64 B
  int*   off           = (int*)(ws + 196672);               // 64 B
  unsigned short* Xb   = (unsigned short*)(ws + 262144);    // 8 MB
  unsigned short* Wcat = Xb   + (size_t)4096 * 1024;        // 32 MB
  unsigned short* Wdt  = Wcat + (size_t)4 * 4096 * 1024;    // 16 MB
  unsigned short* H    = Wdt  + (size_t)4 * 1024 * 2048;    // 9216x2048 bf16 = 37.75 MB
  unsigned short* Y    = Xb;  // [2][9216][1024] bf16 = 37.75 MB, overlaps dead
  // Xb+Wcat (40 MB) — gemm1 finished reading them before gemm2 writes Y.

  hipMemsetAsync(cnt, 0, 16, stream);
  k_routing<<<1024, 256, 0, stream>>>(x, wgate, cw, idx, cnt, Xb, pos);
  k_offsets<<<1, 64, 0, stream>>>(cnt, off);
  k_tcvt_all<<<dim3(32, 16, 12), dim3(64, 4), 0, stream>>>(wgp, wup, wdp, Wcat, Wdt);

  k_gemm1<<<576, 512, 0, stream>>>(Xb, Wcat, H, idx, cnt, off);
  k_gemm2<<<288, 512, 0, stream>>>(H, Wdt, cnt, off, Y);
  k_combine<<<4096, 256, 0, stream>>>(Y, pos, cw, off, out);
}

// Round 23
// 295.521 us; speedup vs baseline: 1.0215x; 1.0215x over previous
//
#include <hip/hip_runtime.h>
#include <hip/hip_bf16.h>
#include <math.h>

// QwenStyleSparseMoEBlock: T=4096, D=1024, F=2048, E=4, top-2.
// R23: corrected issue-before-wait (R22 raced: barrier BEFORE per-wave vmcnt
// wait certified nothing cross-wave -> NaN). Correct order per K-tile:
//   issue T(kt+1) -> wait vmcnt(8) [own T(kt) landed, T(kt+1) in flight]
//   -> s_barrier [ALL waves' T(kt) landed] -> compute(cur)
//   -> s_barrier [reads done; next iter may write cur].
// +1 barrier/iter vs R14; wait now retires loads issued a full iteration + 
// stall earlier. Both GEMMs. Rest = R14-exact (288.5us, absmax 4.15e-3).

typedef float  f32x4 __attribute__((ext_vector_type(4)));
typedef short  s16x8 __attribute__((ext_vector_type(8)));

__device__ __forceinline__ unsigned short f2bf(float f) {
  union { float f; unsigned int u; } v; v.f = f;
  return (unsigned short)((v.u + 0x7fffu + ((v.u >> 16) & 1u)) >> 16);  // RNE
}
__device__ __forceinline__ float bf2f(unsigned short b) {
  union { unsigned int u; float f; } v; v.u = ((unsigned int)b) << 16;
  return v.f;
}

__device__ __forceinline__ void glds16(const void* g, void* l) {
  __builtin_amdgcn_global_load_lds(
      (const __attribute__((address_space(1))) void*)g,
      (__attribute__((address_space(3))) void*)l, 16, 0, 0);
}

// ---------------- routing + X conversion + pos ----------------
__global__ void k_routing(const float* __restrict__ x, const float* __restrict__ wg,
                          float* __restrict__ cw, int* __restrict__ idx,
                          int* __restrict__ cnt, unsigned short* __restrict__ Xb,
                          int4* __restrict__ pos) {
  const int lane = threadIdx.x & 63;
  const int tok  = blockIdx.x * 4 + (threadIdx.x >> 6);
  const float4* X4 = (const float4*)x + (size_t)tok * 256;
  const float4* W4 = (const float4*)wg;
  ushort4* O4 = (ushort4*)Xb + (size_t)tok * 256;
  float a0 = 0.f, a1 = 0.f, a2 = 0.f, a3 = 0.f;
#pragma unroll
  for (int j = 0; j < 4; ++j) {
    const int d4 = j * 64 + lane;
    const float4 v = X4[d4];
    ushort4 o;
    o.x = f2bf(v.x); o.y = f2bf(v.y); o.z = f2bf(v.z); o.w = f2bf(v.w);
    O4[d4] = o;
    float4 w;
    w = W4[0 * 256 + d4]; a0 += v.x * w.x + v.y * w.y + v.z * w.z + v.w * w.w;
    w = W4[1 * 256 + d4]; a1 += v.x * w.x + v.y * w.y + v.z * w.z + v.w * w.w;
    w = W4[2 * 256 + d4]; a2 += v.x * w.x + v.y * w.y + v.z * w.z + v.w * w.w;
    w = W4[3 * 256 + d4]; a3 += v.x * w.x + v.y * w.y + v.z * w.z + v.w * w.w;
  }
#pragma unroll
  for (int off = 32; off; off >>= 1) {
    a0 += __shfl_xor(a0, off);
    a1 += __shfl_xor(a1, off);
    a2 += __shfl_xor(a2, off);
    a3 += __shfl_xor(a3, off);
  }
  if (lane == 0) {
    float l[4] = {a0, a1, a2, a3};
    const float m = fmaxf(fmaxf(l[0], l[1]), fmaxf(l[2], l[3]));
    float p[4];
#pragma unroll
    for (int e = 0; e < 4; ++e) p[e] = expf(l[e] - m);
    int i1 = 0; float b1 = p[0];
#pragma unroll
    for (int e = 1; e < 4; ++e) if (p[e] > b1) { b1 = p[e]; i1 = e; }
    int i2 = -1; float b2 = -1.f;
#pragma unroll
    for (int e = 0; e < 4; ++e) if (e != i1 && p[e] > b2) { b2 = p[e]; i2 = e; }
    const float inv = 1.f / (b1 + b2);
    float o[4] = {0.f, 0.f, 0.f, 0.f};
    o[i1] = b1 * inv; o[i2] = b2 * inv;
    *(float4*)(cw + (size_t)tok * 4) = make_float4(o[0], o[1], o[2], o[3]);
    const int p1 = atomicAdd(&cnt[i1], 1); idx[i1 * 4096 + p1] = tok;
    const int p2 = atomicAdd(&cnt[i2], 1); idx[i2 * 4096 + p2] = tok;
    pos[tok] = make_int4(i1, p1, i2, p2);
  }
}

// off[0..3]=row base (pad-256); off[4..8]=prefix of ceil256 (GEMM1 tiles);
// off[9..13]=prefix of ceil128 (GEMM2 tiles)
__global__ void k_offsets(const int* __restrict__ cnt, int* __restrict__ off) {
  if (threadIdx.x == 0 && blockIdx.x == 0) {
    int o = 0, q = 0, p = 0;
#pragma unroll
    for (int e = 0; e < 4; ++e) {
      off[e] = o; off[4 + e] = q; off[9 + e] = p;
      o += (cnt[e] + 255) & ~255;
      q += (cnt[e] + 255) >> 8;
      p += (cnt[e] + 127) >> 7;
    }
    off[8] = q; off[13] = p;
  }
}

// ---------------- weights -> transposed bf16; gate/up interleaved into Wcat ----------------
__global__ void k_tcvt_all(const float* __restrict__ wgp, const float* __restrict__ wup,
                           const float* __restrict__ wdp,
                           unsigned short* __restrict__ Wcat,
                           unsigned short* __restrict__ Wdt) {
  __shared__ float t[64][65];
  const int z = blockIdx.z;
  const int tx = threadIdx.x, ty = threadIdx.y;
  const float* in; unsigned short* outp; int R, C, c0, r0, cat = 0, addup = 0;
  if (z < 8) {
    R = 1024; C = 2048;
    const int e = z & 3;
    in   = (z < 4 ? wgp : wup) + (size_t)e * 1024 * 2048;
    outp = Wcat + (size_t)e * 4096 * 1024;
    c0 = blockIdx.x * 64; r0 = blockIdx.y * 64;
    cat = 1; addup = (z >= 4) ? 16 : 0;
  } else {
    R = 2048; C = 1024;
    const int e = z & 3;
    in   = wdp + (size_t)e * 2048 * 1024;
    outp = Wdt + (size_t)e * 2048 * 1024;
    c0 = blockIdx.y * 64; r0 = blockIdx.x * 64;
  }
#pragma unroll
  for (int i = 0; i < 16; ++i) {
    const int r = i * 4 + ty;
    t[r][tx] = in[(size_t)(r0 + r) * C + c0 + tx];
  }
  __syncthreads();
#pragma unroll
  for (int i = 0; i < 16; ++i) {
    const int cc = i * 4 + ty;
    const int f = c0 + cc;
    const int orow = cat ? (((f >> 4) << 5) + (f & 15) + addup) : f;
    outp[(size_t)orow * R + r0 + tx] = f2bf(t[tx][cc]);
  }
}

// ---------------- GEMM1: H = gelu(Xg@Wg)*(Xg@Wu), 256x256 ----------------
// grid 576 = 16 bn x 36 mt, bn-major XCD chunks (chunk=72)
__global__ __launch_bounds__(512, 2)
void k_gemm1(const unsigned short* __restrict__ Xb,
             const unsigned short* __restrict__ Wcat,
             unsigned short* __restrict__ H,
             const int* __restrict__ idx, const int* __restrict__ cnt,
             const int* __restrict__ off) {
  const int w0 = (blockIdx.x & 7) * 72 + (blockIdx.x >> 3);
  const int bn = w0 / 36, mt = w0 % 36;
  const int* t1 = off + 4;
  if (mt >= t1[4]) return;
  const int e = (mt >= t1[1]) + (mt >= t1[2]) + (mt >= t1[3]);
  const int local = mt - t1[e];
  const int cn = cnt[e];
  const int lr0 = local * 256;
  const int hrow0 = off[e] + lr0;

  __shared__ __align__(16) unsigned short lds[2][2][256 * 64];  // 128 KiB

  const int tid = threadIdx.x;
  const int lane = tid & 63, wv = tid >> 6;
  const int wm = wv >> 2, wn = wv & 3;            // 2 x 4 waves
  const int l15 = lane & 15;
  const int kb0 = ((lane >> 4) * 16) ^ ((lane & 7) << 4);
  const int kb1 = kb0 ^ 64;
  const int lrow = lane >> 3;
  const int scol = ((lane & 7) ^ lrow) * 8;
  const int wbase = wv * 8;

  int tk[4];
#pragma unroll
  for (int j = 0; j < 4; ++j)
    tk[j] = idx[e * 4096 + min(lr0 + j * 64 + wbase + lrow, cn - 1)];

  const unsigned short* Wb = Wcat + (size_t)e * 4096 * 1024 + (size_t)(bn * 256) * 1024;

  f32x4 acc[8][4] = {};

#pragma unroll
  for (int j = 0; j < 4; ++j)
    glds16(Xb + (size_t)tk[j] * 1024 + scol, &lds[0][0][(j * 64 + wbase) * 64]);
#pragma unroll
  for (int j = 0; j < 4; ++j)
    glds16(Wb + (size_t)(j * 64 + wbase + lrow) * 1024 + scol, &lds[0][1][(j * 64 + wbase) * 64]);

  for (int kt = 0; kt < 16; ++kt) {
    const int cur = kt & 1;
    if (kt < 15) {
      const int ko = (kt + 1) * 64;
#pragma unroll
      for (int j = 0; j < 4; ++j)
        glds16(Xb + (size_t)tk[j] * 1024 + ko + scol, &lds[cur ^ 1][0][(j * 64 + wbase) * 64]);
#pragma unroll
      for (int j = 0; j < 4; ++j)
        glds16(Wb + (size_t)(j * 64 + wbase + lrow) * 1024 + ko + scol, &lds[cur ^ 1][1][(j * 64 + wbase) * 64]);
      asm volatile("s_waitcnt vmcnt(8)" ::: "memory");  // own T(kt) landed; T(kt+1) in flight
    } else {
      asm volatile("s_waitcnt vmcnt(0)" ::: "memory");
    }
    asm volatile("s_barrier" ::: "memory");             // ALL waves' T(kt) landed
    const char* Ab = (const char*)lds[cur][0];
    const char* Bb = (const char*)lds[cur][1];
    s16x8 bfr[4][2];
#pragma unroll
    for (int ni = 0; ni < 4; ++ni) {
      const int row = wn * 64 + ni * 16 + l15;
      bfr[ni][0] = *(const s16x8*)(Bb + row * 128 + kb0);
      bfr[ni][1] = *(const s16x8*)(Bb + row * 128 + kb1);
    }
#pragma unroll
    for (int p = 0; p < 4; ++p) {
      const int r0a = wm * 128 + (2 * p) * 16 + l15;
      const int r1a = wm * 128 + (2 * p + 1) * 16 + l15;
      const s16x8 a0k0 = *(const s16x8*)(Ab + r0a * 128 + kb0);
      const s16x8 a0k1 = *(const s16x8*)(Ab + r0a * 128 + kb1);
      const s16x8 a1k0 = *(const s16x8*)(Ab + r1a * 128 + kb0);
      const s16x8 a1k1 = *(const s16x8*)(Ab + r1a * 128 + kb1);
      __builtin_amdgcn_s_setprio(1);
#pragma unroll
      for (int ni = 0; ni < 4; ++ni) {
        acc[2 * p][ni]     = __builtin_amdgcn_mfma_f32_16x16x32_bf16(a0k0, bfr[ni][0], acc[2 * p][ni], 0, 0, 0);
        acc[2 * p][ni]     = __builtin_amdgcn_mfma_f32_16x16x32_bf16(a0k1, bfr[ni][1], acc[2 * p][ni], 0, 0, 0);
        acc[2 * p + 1][ni] = __builtin_amdgcn_mfma_f32_16x16x32_bf16(a1k0, bfr[ni][0], acc[2 * p + 1][ni], 0, 0, 0);
        acc[2 * p + 1][ni] = __builtin_amdgcn_mfma_f32_16x16x32_bf16(a1k1, bfr[ni][1], acc[2 * p + 1][ni], 0, 0, 0);
      }
      __builtin_amdgcn_s_setprio(0);
    }
    asm volatile("s_barrier" ::: "memory");             // reads of cur done
  }

  const int rbase = hrow0 + wm * 128;
#pragma unroll
  for (int mi = 0; mi < 8; ++mi)
#pragma unroll
    for (int q = 0; q < 2; ++q)
#pragma unroll
      for (int r = 0; r < 4; ++r) {
        const int row = rbase + mi * 16 + (lane >> 4) * 4 + r;
        const int col = bn * 128 + wn * 32 + q * 16 + l15;
        const float g = acc[mi][2 * q][r];
        const float u = acc[mi][2 * q + 1][r];
        const float h = 0.5f * g * (1.0f + erff(g * 0.70710678118654752f)) * u;
        H[(size_t)row * 2048 + col] = f2bf(h);
      }
}

// ---------------- GEMM2: Y[kh] = H_e[:,kh] @ Wd_e[kh,:] (split-K) ----------------
// grid 1088 = 2 kh x 68 mt x 8 bn; XCD chunks of 136 (R14 decode)
__global__ __launch_bounds__(256, 2)
void k_gemm2(const unsigned short* __restrict__ H,
             const unsigned short* __restrict__ Wdt,
             const int* __restrict__ cnt, const int* __restrict__ off,
             unsigned short* __restrict__ Y) {
  const int w = (blockIdx.x & 7) * 136 + (blockIdx.x >> 3);  // bijective, 1088=8*136
  const int kh = (w >= 544) ? 1 : 0;
  const int w2 = w - kh * 544;
  const int mt = w2 >> 3, bn = w2 & 7;
  const int* t2 = off + 9;
  if (mt >= t2[4]) return;
  const int e = (mt >= t2[1]) + (mt >= t2[2]) + (mt >= t2[3]);
  const int local = mt - t2[e];
  const int lr0 = local * 128;
  const int hrow0 = off[e] + lr0;

  __shared__ __align__(16) unsigned short lds[2][2][128 * 64];  // 64 KiB

  const int lane = threadIdx.x & 63, wid = threadIdx.x >> 6;
  const int wm = wid >> 1, wn = wid & 1;
  const int l15 = lane & 15;
  const int kb0 = ((lane >> 4) * 16) ^ ((lane & 7) << 4);
  const int kb1 = kb0 ^ 64;
  const int lrow = lane >> 3;
  const int scol = ((lane & 7) ^ lrow) * 8;
  const int wbase = wid * 8;

  const unsigned short* Ha = H + (size_t)hrow0 * 2048 + kh * 1024;
  const unsigned short* Wd = Wdt + (size_t)e * 1024 * 2048 + (size_t)(bn * 128) * 2048 + kh * 1024;

  f32x4 acc[4][4] = {};

#pragma unroll
  for (int j = 0; j < 4; ++j) {
    const int r = j * 32 + wbase;
    glds16(Ha + (size_t)(r + lrow) * 2048 + scol, &lds[0][0][r * 64]);
    glds16(Wd + (size_t)(r + lrow) * 2048 + scol, &lds[0][1][r * 64]);
  }

  for (int kt = 0; kt < 16; ++kt) {
    const int cur = kt & 1;
    if (kt < 15) {
      const int ko = (kt + 1) * 64;
#pragma unroll
      for (int j = 0; j < 4; ++j) {
        const int r = j * 32 + wbase;
        glds16(Ha + (size_t)(r + lrow) * 2048 + ko + scol, &lds[cur ^ 1][0][r * 64]);
        glds16(Wd + (size_t)(r + lrow) * 2048 + ko + scol, &lds[cur ^ 1][1][r * 64]);
      }
      asm volatile("s_waitcnt vmcnt(8)" ::: "memory");
    } else {
      asm volatile("s_waitcnt vmcnt(0)" ::: "memory");
    }
    asm volatile("s_barrier" ::: "memory");
    const char* Ab = (const char*)lds[cur][0];
    const char* Bb = (const char*)lds[cur][1];
    s16x8 bfr[4][2];
#pragma unroll
    for (int ni = 0; ni < 4; ++ni) {
      const int row = wn * 64 + ni * 16 + l15;
      bfr[ni][0] = *(const s16x8*)(Bb + row * 128 + kb0);
      bfr[ni][1] = *(const s16x8*)(Bb + row * 128 + kb1);
    }
#pragma unroll
    for (int mi = 0; mi < 4; ++mi) {
      const int ra = wm * 64 + mi * 16 + l15;
      const s16x8 ak0 = *(const s16x8*)(Ab + ra * 128 + kb0);
      const s16x8 ak1 = *(const s16x8*)(Ab + ra * 128 + kb1);
      __builtin_amdgcn_s_setprio(1);
#pragma unroll
      for (int ni = 0; ni < 4; ++ni) {
        acc[mi][ni] = __builtin_amdgcn_mfma_f32_16x16x32_bf16(ak0, bfr[ni][0], acc[mi][ni], 0, 0, 0);
        acc[mi][ni] = __builtin_amdgcn_mfma_f32_16x16x32_bf16(ak1, bfr[ni][1], acc[mi][ni], 0, 0, 0);
      }
      __builtin_amdgcn_s_setprio(0);
    }
    asm volatile("s_barrier" ::: "memory");
  }

  // plain packed stores into this K-half's Y
  unsigned short* Yk = Y + (size_t)kh * 9216 * 1024;
  const int rbase = hrow0 + wm * 64;
#pragma unroll
  for (int mi = 0; mi < 4; ++mi)
#pragma unroll
    for (int r = 0; r < 4; ++r) {
      const int row = rbase + mi * 16 + (lane >> 4) * 4 + r;
      unsigned short* yrow = Yk + (size_t)row * 1024 + bn * 128 + wn * 64 + l15;
#pragma unroll
      for (int ni = 0; ni < 4; ++ni)
        yrow[ni * 16] = f2bf(acc[mi][ni][r]);
    }
}

// ---------------- combine: out[tok] = w1*(Y0[r1]+Y1[r1]) + w2*(Y0[r2]+Y1[r2]) ----------------
__global__ void k_combine(const unsigned short* __restrict__ Y,
                          const int4* __restrict__ pos,
                          const float* __restrict__ cw,
                          const int* __restrict__ off,
                          float* __restrict__ out) {
  const int tok = blockIdx.x;
  const int d4 = threadIdx.x;   // 256 threads, 4 floats each
  const int4 p = pos[tok];
  const int r1 = off[p.x] + p.y;
  const int r2 = off[p.z] + p.w;
  const float w1 = cw[(size_t)tok * 4 + p.x];
  const float w2 = cw[(size_t)tok * 4 + p.z];
  const unsigned short* Y1p = Y + (size_t)9216 * 1024;
  const ushort4 a1 = ((const ushort4*)(Y   + (size_t)r1 * 1024))[d4];
  const ushort4 b1 = ((const ushort4*)(Y1p + (size_t)r1 * 1024))[d4];
  const ushort4 a2 = ((const ushort4*)(Y   + (size_t)r2 * 1024))[d4];
  const ushort4 b2 = ((const ushort4*)(Y1p + (size_t)r2 * 1024))[d4];
  float4 o;
  o.x = w1 * (bf2f(a1.x) + bf2f(b1.x)) + w2 * (bf2f(a2.x) + bf2f(b2.x));
  o.y = w1 * (bf2f(a1.y) + bf2f(b1.y)) + w2 * (bf2f(a2.y) + bf2f(b2.y));
  o.z = w1 * (bf2f(a1.z) + bf2f(b1.z)) + w2 * (bf2f(a2.z) + bf2f(b2.z));
  o.w = w1 * (bf2f(a1.w) + bf2f(b1.w)) + w2 * (bf2f(a2.w) + bf2f(b2.w));
  ((float4*)(out + (size_t)tok * 1024))[d4] = o;
}

extern "C" void kernel_launch(void* const* d_in, const int* in_sizes, int n_in,
                              void* d_out, int out_size, void* d_ws, size_t ws_size,
                              hipStream_t stream) {
  const float* x     = (const float*)d_in[0];
  const float* wgate = (const float*)d_in[1];
  const float* wgp   = (const float*)d_in[2];
  const float* wup   = (const float*)d_in[3];
  const float* wdp   = (const float*)d_in[4];
  float* out = (float*)d_out;

  char* ws = (char*)d_ws;
  float* cw            = (float*)ws;                        // 64 KB
  int*   idx           = (int*)(ws + 65536);                // 64 KB
  int4*  pos           = (int4*)(ws + 131072);              // 64 KB
  int*   cnt           = (int*)(ws + 196608);               // 64 B
  int*   off           = (int*)(ws + 196672);               // 64 B
  unsigned short* Xb   = (unsigned short*)(ws + 262144);    // 8 MB
  unsigned short* Wcat = Xb   + (size_t)4096 * 1024;        // 32 MB
  unsigned short* Wdt  = Wcat + (size_t)4 * 4096 * 1024;    // 16 MB
  unsigned short* H    = Wdt  + (size_t)4 * 1024 * 2048;    // 9216x2048 bf16 = 37.75 MB
  unsigned short* Y    = Xb;  // [2][9216][1024] bf16 = 37.75 MB, overlaps dead
  // Xb+Wcat (40 MB) — gemm1 finished reading them before gemm2 writes Y.

  hipMemsetAsync(cnt, 0, 16, stream);
  k_routing<<<1024, 256, 0, stream>>>(x, wgate, cw, idx, cnt, Xb, pos);
  k_offsets<<<1, 64, 0, stream>>>(cnt, off);
  k_tcvt_all<<<dim3(32, 16, 12), dim3(64, 4), 0, stream>>>(wgp, wup, wdp, Wcat, Wdt);

  k_gemm1<<<576, 512, 0, stream>>>(Xb, Wcat, H, idx, cnt, off);
  k_gemm2<<<1088, 256, 0, stream>>>(H, Wdt, cnt, off, Y);
  k_combine<<<4096, 256, 0, stream>>>(Y, pos, cw, off, out);
}

// Round 24
// 287.789 us; speedup vs baseline: 1.0490x; 1.0269x over previous
//
#include <hip/hip_runtime.h>
#include <hip/hip_bf16.h>
#include <math.h>

// QwenStyleSparseMoEBlock: T=4096, D=1024, F=2048, E=4, top-2.
// R24: FINAL = R14-exact revert (session best: 288.5us, absmax 4.15e-3).
// Schedule-variant ledger vs R14: R18 depth-2 312.8 / R19 TLP 293.3 /
// R20 bn-major 297.8 / R21 256^2 301.9 / R22 race / R23 issue-first 295.5.
// Pipeline: fused routing+X->bf16 -> weight transpose (gate/up interleaved
// Wcat) -> gather-GEMM1 256x256 T3-min counted (G4 swizzle, 0 bank conflicts)
// -> split-K x2 non-atomic GEMM2 128x128 -> 4-row fp32 combine.

typedef float  f32x4 __attribute__((ext_vector_type(4)));
typedef short  s16x8 __attribute__((ext_vector_type(8)));

__device__ __forceinline__ unsigned short f2bf(float f) {
  union { float f; unsigned int u; } v; v.f = f;
  return (unsigned short)((v.u + 0x7fffu + ((v.u >> 16) & 1u)) >> 16);  // RNE
}
__device__ __forceinline__ float bf2f(unsigned short b) {
  union { unsigned int u; float f; } v; v.u = ((unsigned int)b) << 16;
  return v.f;
}

__device__ __forceinline__ void glds16(const void* g, void* l) {
  __builtin_amdgcn_global_load_lds(
      (const __attribute__((address_space(1))) void*)g,
      (__attribute__((address_space(3))) void*)l, 16, 0, 0);
}

// ---------------- routing + X conversion + pos ----------------
__global__ void k_routing(const float* __restrict__ x, const float* __restrict__ wg,
                          float* __restrict__ cw, int* __restrict__ idx,
                          int* __restrict__ cnt, unsigned short* __restrict__ Xb,
                          int4* __restrict__ pos) {
  const int lane = threadIdx.x & 63;
  const int tok  = blockIdx.x * 4 + (threadIdx.x >> 6);
  const float4* X4 = (const float4*)x + (size_t)tok * 256;
  const float4* W4 = (const float4*)wg;
  ushort4* O4 = (ushort4*)Xb + (size_t)tok * 256;
  float a0 = 0.f, a1 = 0.f, a2 = 0.f, a3 = 0.f;
#pragma unroll
  for (int j = 0; j < 4; ++j) {
    const int d4 = j * 64 + lane;
    const float4 v = X4[d4];
    ushort4 o;
    o.x = f2bf(v.x); o.y = f2bf(v.y); o.z = f2bf(v.z); o.w = f2bf(v.w);
    O4[d4] = o;
    float4 w;
    w = W4[0 * 256 + d4]; a0 += v.x * w.x + v.y * w.y + v.z * w.z + v.w * w.w;
    w = W4[1 * 256 + d4]; a1 += v.x * w.x + v.y * w.y + v.z * w.z + v.w * w.w;
    w = W4[2 * 256 + d4]; a2 += v.x * w.x + v.y * w.y + v.z * w.z + v.w * w.w;
    w = W4[3 * 256 + d4]; a3 += v.x * w.x + v.y * w.y + v.z * w.z + v.w * w.w;
  }
#pragma unroll
  for (int off = 32; off; off >>= 1) {
    a0 += __shfl_xor(a0, off);
    a1 += __shfl_xor(a1, off);
    a2 += __shfl_xor(a2, off);
    a3 += __shfl_xor(a3, off);
  }
  if (lane == 0) {
    float l[4] = {a0, a1, a2, a3};
    const float m = fmaxf(fmaxf(l[0], l[1]), fmaxf(l[2], l[3]));
    float p[4];
#pragma unroll
    for (int e = 0; e < 4; ++e) p[e] = expf(l[e] - m);
    int i1 = 0; float b1 = p[0];
#pragma unroll
    for (int e = 1; e < 4; ++e) if (p[e] > b1) { b1 = p[e]; i1 = e; }
    int i2 = -1; float b2 = -1.f;
#pragma unroll
    for (int e = 0; e < 4; ++e) if (e != i1 && p[e] > b2) { b2 = p[e]; i2 = e; }
    const float inv = 1.f / (b1 + b2);
    float o[4] = {0.f, 0.f, 0.f, 0.f};
    o[i1] = b1 * inv; o[i2] = b2 * inv;
    *(float4*)(cw + (size_t)tok * 4) = make_float4(o[0], o[1], o[2], o[3]);
    const int p1 = atomicAdd(&cnt[i1], 1); idx[i1 * 4096 + p1] = tok;
    const int p2 = atomicAdd(&cnt[i2], 1); idx[i2 * 4096 + p2] = tok;
    pos[tok] = make_int4(i1, p1, i2, p2);
  }
}

// off[0..3]=row base (pad-256); off[4..8]=prefix of ceil256 (GEMM1 tiles);
// off[9..13]=prefix of ceil128 (GEMM2 tiles)
__global__ void k_offsets(const int* __restrict__ cnt, int* __restrict__ off) {
  if (threadIdx.x == 0 && blockIdx.x == 0) {
    int o = 0, q = 0, p = 0;
#pragma unroll
    for (int e = 0; e < 4; ++e) {
      off[e] = o; off[4 + e] = q; off[9 + e] = p;
      o += (cnt[e] + 255) & ~255;
      q += (cnt[e] + 255) >> 8;
      p += (cnt[e] + 127) >> 7;
    }
    off[8] = q; off[13] = p;
  }
}

// ---------------- weights -> transposed bf16; gate/up interleaved into Wcat ----------------
__global__ void k_tcvt_all(const float* __restrict__ wgp, const float* __restrict__ wup,
                           const float* __restrict__ wdp,
                           unsigned short* __restrict__ Wcat,
                           unsigned short* __restrict__ Wdt) {
  __shared__ float t[64][65];
  const int z = blockIdx.z;
  const int tx = threadIdx.x, ty = threadIdx.y;
  const float* in; unsigned short* outp; int R, C, c0, r0, cat = 0, addup = 0;
  if (z < 8) {
    R = 1024; C = 2048;
    const int e = z & 3;
    in   = (z < 4 ? wgp : wup) + (size_t)e * 1024 * 2048;
    outp = Wcat + (size_t)e * 4096 * 1024;
    c0 = blockIdx.x * 64; r0 = blockIdx.y * 64;
    cat = 1; addup = (z >= 4) ? 16 : 0;
  } else {
    R = 2048; C = 1024;
    const int e = z & 3;
    in   = wdp + (size_t)e * 2048 * 1024;
    outp = Wdt + (size_t)e * 2048 * 1024;
    c0 = blockIdx.y * 64; r0 = blockIdx.x * 64;
  }
#pragma unroll
  for (int i = 0; i < 16; ++i) {
    const int r = i * 4 + ty;
    t[r][tx] = in[(size_t)(r0 + r) * C + c0 + tx];
  }
  __syncthreads();
#pragma unroll
  for (int i = 0; i < 16; ++i) {
    const int cc = i * 4 + ty;
    const int f = c0 + cc;
    const int orow = cat ? (((f >> 4) << 5) + (f & 15) + addup) : f;
    outp[(size_t)orow * R + r0 + tx] = f2bf(t[tx][cc]);
  }
}

// ---------------- GEMM1: H = gelu(Xg@Wg)*(Xg@Wu), 256x256, T3-min counted ----------------
// grid 576 = 16 bn x 36 mt, bn-major XCD chunks (chunk=72)
__global__ __launch_bounds__(512, 2)
void k_gemm1(const unsigned short* __restrict__ Xb,
             const unsigned short* __restrict__ Wcat,
             unsigned short* __restrict__ H,
             const int* __restrict__ idx, const int* __restrict__ cnt,
             const int* __restrict__ off) {
  const int w0 = (blockIdx.x & 7) * 72 + (blockIdx.x >> 3);
  const int bn = w0 / 36, mt = w0 % 36;
  const int* t1 = off + 4;
  if (mt >= t1[4]) return;
  const int e = (mt >= t1[1]) + (mt >= t1[2]) + (mt >= t1[3]);
  const int local = mt - t1[e];
  const int cn = cnt[e];
  const int lr0 = local * 256;
  const int hrow0 = off[e] + lr0;

  __shared__ __align__(16) unsigned short lds[2][2][256 * 64];  // 128 KiB

  const int tid = threadIdx.x;
  const int lane = tid & 63, wv = tid >> 6;
  const int wm = wv >> 2, wn = wv & 3;            // 2 x 4 waves
  const int l15 = lane & 15;
  const int kb0 = ((lane >> 4) * 16) ^ ((lane & 7) << 4);
  const int kb1 = kb0 ^ 64;
  const int lrow = lane >> 3;
  const int scol = ((lane & 7) ^ lrow) * 8;
  const int wbase = wv * 8;

  int tk[4];
#pragma unroll
  for (int j = 0; j < 4; ++j)
    tk[j] = idx[e * 4096 + min(lr0 + j * 64 + wbase + lrow, cn - 1)];

  const unsigned short* Wb = Wcat + (size_t)e * 4096 * 1024 + (size_t)(bn * 256) * 1024;

  f32x4 acc[8][4] = {};

#pragma unroll
  for (int j = 0; j < 4; ++j)
    glds16(Xb + (size_t)tk[j] * 1024 + scol, &lds[0][0][(j * 64 + wbase) * 64]);
#pragma unroll
  for (int j = 0; j < 4; ++j)
    glds16(Wb + (size_t)(j * 64 + wbase + lrow) * 1024 + scol, &lds[0][1][(j * 64 + wbase) * 64]);

  for (int kt = 0; kt < 16; ++kt) {
    const int cur = kt & 1;
    asm volatile("s_waitcnt vmcnt(0)" ::: "memory");
    asm volatile("s_barrier" ::: "memory");
    if (kt < 15) {
      const int ko = (kt + 1) * 64;
#pragma unroll
      for (int j = 0; j < 4; ++j)
        glds16(Xb + (size_t)tk[j] * 1024 + ko + scol, &lds[cur ^ 1][0][(j * 64 + wbase) * 64]);
#pragma unroll
      for (int j = 0; j < 4; ++j)
        glds16(Wb + (size_t)(j * 64 + wbase + lrow) * 1024 + ko + scol, &lds[cur ^ 1][1][(j * 64 + wbase) * 64]);
    }
    const char* Ab = (const char*)lds[cur][0];
    const char* Bb = (const char*)lds[cur][1];
    s16x8 bfr[4][2];
#pragma unroll
    for (int ni = 0; ni < 4; ++ni) {
      const int row = wn * 64 + ni * 16 + l15;
      bfr[ni][0] = *(const s16x8*)(Bb + row * 128 + kb0);
      bfr[ni][1] = *(const s16x8*)(Bb + row * 128 + kb1);
    }
#pragma unroll
    for (int p = 0; p < 4; ++p) {
      const int r0a = wm * 128 + (2 * p) * 16 + l15;
      const int r1a = wm * 128 + (2 * p + 1) * 16 + l15;
      const s16x8 a0k0 = *(const s16x8*)(Ab + r0a * 128 + kb0);
      const s16x8 a0k1 = *(const s16x8*)(Ab + r0a * 128 + kb1);
      const s16x8 a1k0 = *(const s16x8*)(Ab + r1a * 128 + kb0);
      const s16x8 a1k1 = *(const s16x8*)(Ab + r1a * 128 + kb1);
      __builtin_amdgcn_s_setprio(1);
#pragma unroll
      for (int ni = 0; ni < 4; ++ni) {
        acc[2 * p][ni]     = __builtin_amdgcn_mfma_f32_16x16x32_bf16(a0k0, bfr[ni][0], acc[2 * p][ni], 0, 0, 0);
        acc[2 * p][ni]     = __builtin_amdgcn_mfma_f32_16x16x32_bf16(a0k1, bfr[ni][1], acc[2 * p][ni], 0, 0, 0);
        acc[2 * p + 1][ni] = __builtin_amdgcn_mfma_f32_16x16x32_bf16(a1k0, bfr[ni][0], acc[2 * p + 1][ni], 0, 0, 0);
        acc[2 * p + 1][ni] = __builtin_amdgcn_mfma_f32_16x16x32_bf16(a1k1, bfr[ni][1], acc[2 * p + 1][ni], 0, 0, 0);
      }
      __builtin_amdgcn_s_setprio(0);
    }
  }

  const int rbase = hrow0 + wm * 128;
#pragma unroll
  for (int mi = 0; mi < 8; ++mi)
#pragma unroll
    for (int q = 0; q < 2; ++q)
#pragma unroll
      for (int r = 0; r < 4; ++r) {
        const int row = rbase + mi * 16 + (lane >> 4) * 4 + r;
        const int col = bn * 128 + wn * 32 + q * 16 + l15;
        const float g = acc[mi][2 * q][r];
        const float u = acc[mi][2 * q + 1][r];
        const float h = 0.5f * g * (1.0f + erff(g * 0.70710678118654752f)) * u;
        H[(size_t)row * 2048 + col] = f2bf(h);
      }
}

// ---------------- GEMM2: Y[kh] = H_e[:,kh] @ Wd_e[kh,:] (split-K, no atomics) ----------------
// grid 1088 = 2 kh x 68 mt x 8 bn; XCD chunks of 136 (XCDs 0-3 kh=0, 4-7 kh=1)
__global__ __launch_bounds__(256, 2)
void k_gemm2(const unsigned short* __restrict__ H,
             const unsigned short* __restrict__ Wdt,
             const int* __restrict__ cnt, const int* __restrict__ off,
             unsigned short* __restrict__ Y) {
  const int w = (blockIdx.x & 7) * 136 + (blockIdx.x >> 3);  // bijective, 1088=8*136
  const int kh = (w >= 544) ? 1 : 0;
  const int w2 = w - kh * 544;
  const int mt = w2 >> 3, bn = w2 & 7;
  const int* t2 = off + 9;
  if (mt >= t2[4]) return;
  const int e = (mt >= t2[1]) + (mt >= t2[2]) + (mt >= t2[3]);
  const int local = mt - t2[e];
  const int lr0 = local * 128;
  const int hrow0 = off[e] + lr0;

  __shared__ __align__(16) unsigned short lds[2][2][128 * 64];  // 64 KiB

  const int lane = threadIdx.x & 63, wid = threadIdx.x >> 6;
  const int wm = wid >> 1, wn = wid & 1;
  const int l15 = lane & 15;
  const int kb0 = ((lane >> 4) * 16) ^ ((lane & 7) << 4);
  const int kb1 = kb0 ^ 64;
  const int lrow = lane >> 3;
  const int scol = ((lane & 7) ^ lrow) * 8;
  const int wbase = wid * 8;

  const unsigned short* Ha = H + (size_t)hrow0 * 2048 + kh * 1024;
  const unsigned short* Wd = Wdt + (size_t)e * 1024 * 2048 + (size_t)(bn * 128) * 2048 + kh * 1024;

  f32x4 acc[4][4] = {};

#pragma unroll
  for (int j = 0; j < 4; ++j) {
    const int r = j * 32 + wbase;
    glds16(Ha + (size_t)(r + lrow) * 2048 + scol, &lds[0][0][r * 64]);
    glds16(Wd + (size_t)(r + lrow) * 2048 + scol, &lds[0][1][r * 64]);
  }

  for (int kt = 0; kt < 16; ++kt) {
    const int cur = kt & 1;
    asm volatile("s_waitcnt vmcnt(0)" ::: "memory");
    asm volatile("s_barrier" ::: "memory");
    if (kt < 15) {
      const int ko = (kt + 1) * 64;
#pragma unroll
      for (int j = 0; j < 4; ++j) {
        const int r = j * 32 + wbase;
        glds16(Ha + (size_t)(r + lrow) * 2048 + ko + scol, &lds[cur ^ 1][0][r * 64]);
        glds16(Wd + (size_t)(r + lrow) * 2048 + ko + scol, &lds[cur ^ 1][1][r * 64]);
      }
    }
    const char* Ab = (const char*)lds[cur][0];
    const char* Bb = (const char*)lds[cur][1];
    s16x8 bfr[4][2];
#pragma unroll
    for (int ni = 0; ni < 4; ++ni) {
      const int row = wn * 64 + ni * 16 + l15;
      bfr[ni][0] = *(const s16x8*)(Bb + row * 128 + kb0);
      bfr[ni][1] = *(const s16x8*)(Bb + row * 128 + kb1);
    }
#pragma unroll
    for (int mi = 0; mi < 4; ++mi) {
      const int ra = wm * 64 + mi * 16 + l15;
      const s16x8 ak0 = *(const s16x8*)(Ab + ra * 128 + kb0);
      const s16x8 ak1 = *(const s16x8*)(Ab + ra * 128 + kb1);
      __builtin_amdgcn_s_setprio(1);
#pragma unroll
      for (int ni = 0; ni < 4; ++ni) {
        acc[mi][ni] = __builtin_amdgcn_mfma_f32_16x16x32_bf16(ak0, bfr[ni][0], acc[mi][ni], 0, 0, 0);
        acc[mi][ni] = __builtin_amdgcn_mfma_f32_16x16x32_bf16(ak1, bfr[ni][1], acc[mi][ni], 0, 0, 0);
      }
      __builtin_amdgcn_s_setprio(0);
    }
  }

  // plain packed stores into this K-half's Y
  unsigned short* Yk = Y + (size_t)kh * 9216 * 1024;
  const int rbase = hrow0 + wm * 64;
#pragma unroll
  for (int mi = 0; mi < 4; ++mi)
#pragma unroll
    for (int r = 0; r < 4; ++r) {
      const int row = rbase + mi * 16 + (lane >> 4) * 4 + r;
      unsigned short* yrow = Yk + (size_t)row * 1024 + bn * 128 + wn * 64 + l15;
#pragma unroll
      for (int ni = 0; ni < 4; ++ni)
        yrow[ni * 16] = f2bf(acc[mi][ni][r]);
    }
}

// ---------------- combine: out[tok] = w1*(Y0[r1]+Y1[r1]) + w2*(Y0[r2]+Y1[r2]) ----------------
__global__ void k_combine(const unsigned short* __restrict__ Y,
                          const int4* __restrict__ pos,
                          const float* __restrict__ cw,
                          const int* __restrict__ off,
                          float* __restrict__ out) {
  const int tok = blockIdx.x;
  const int d4 = threadIdx.x;   // 256 threads, 4 floats each
  const int4 p = pos[tok];
  const int r1 = off[p.x] + p.y;
  const int r2 = off[p.z] + p.w;
  const float w1 = cw[(size_t)tok * 4 + p.x];
  const float w2 = cw[(size_t)tok * 4 + p.z];
  const unsigned short* Y1p = Y + (size_t)9216 * 1024;
  const ushort4 a1 = ((const ushort4*)(Y   + (size_t)r1 * 1024))[d4];
  const ushort4 b1 = ((const ushort4*)(Y1p + (size_t)r1 * 1024))[d4];
  const ushort4 a2 = ((const ushort4*)(Y   + (size_t)r2 * 1024))[d4];
  const ushort4 b2 = ((const ushort4*)(Y1p + (size_t)r2 * 1024))[d4];
  float4 o;
  o.x = w1 * (bf2f(a1.x) + bf2f(b1.x)) + w2 * (bf2f(a2.x) + bf2f(b2.x));
  o.y = w1 * (bf2f(a1.y) + bf2f(b1.y)) + w2 * (bf2f(a2.y) + bf2f(b2.y));
  o.z = w1 * (bf2f(a1.z) + bf2f(b1.z)) + w2 * (bf2f(a2.z) + bf2f(b2.z));
  o.w = w1 * (bf2f(a1.w) + bf2f(b1.w)) + w2 * (bf2f(a2.w) + bf2f(b2.w));
  ((float4*)(out + (size_t)tok * 1024))[d4] = o;
}

extern "C" void kernel_launch(void* const* d_in, const int* in_sizes, int n_in,
                              void* d_out, int out_size, void* d_ws, size_t ws_size,
                              hipStream_t stream) {
  const float* x     = (const float*)d_in[0];
  const float* wgate = (const float*)d_in[1];
  const float* wgp   = (const float*)d_in[2];
  const float* wup   = (const float*)d_in[3];
  const float* wdp   = (const float*)d_in[4];
  float* out = (float*)d_out;

  char* ws = (char*)d_ws;
  float* cw            = (float*)ws;                        // 64 KB
  int*   idx           = (int*)(ws + 65536);                // 64 KB
  int4*  pos           = (int4*)(ws + 131072);              // 64 KB
  int*   cnt           = (int*)(ws + 196608);               // 64 B
  int*   off           = (int*)(ws + 196672);               // 64 B
  unsigned short* Xb   = (unsigned short*)(ws + 262144);    // 8 MB
  unsigned short* Wcat = Xb   + (size_t)4096 * 1024;        // 32 MB
  unsigned short* Wdt  = Wcat + (size_t)4 * 4096 * 1024;    // 16 MB
  unsigned short* H    = Wdt  + (size_t)4 * 1024 * 2048;    // 9216x2048 bf16 = 37.75 MB
  unsigned short* Y    = Xb;  // [2][9216][1024] bf16 = 37.75 MB, overlaps dead
  // Xb+Wcat (40 MB) — gemm1 finished reading them before gemm2 writes Y.

  hipMemsetAsync(cnt, 0, 16, stream);
  k_routing<<<1024, 256, 0, stream>>>(x, wgate, cw, idx, cnt, Xb, pos);
  k_offsets<<<1, 64, 0, stream>>>(cnt, off);
  k_tcvt_all<<<dim3(32, 16, 12), dim3(64, 4), 0, stream>>>(wgp, wup, wdp, Wcat, Wdt);

  k_gemm1<<<576, 512, 0, stream>>>(Xb, Wcat, H, idx, cnt, off);
  k_gemm2<<<1088, 256, 0, stream>>>(H, Wdt, cnt, off, Y);
  k_combine<<<4096, 256, 0, stream>>>(Y, pos, cw, off, out);
}